// Round 9
// baseline (537.453 us; speedup 1.0000x reference)
//
#include <hip/hip_runtime.h>
#include <hip/hip_bf16.h>

#define N_NODES 50000
#define N_EDGES 600000
#define N_GRAPHS 256
#define C 128
#define NB 196            // ceil(N_NODES/256) scan blocks

typedef unsigned short ushort;
typedef unsigned int uint;
typedef __attribute__((ext_vector_type(8))) short bfrag8;
typedef __attribute__((ext_vector_type(4))) float facc4;

// bf16 helpers (bit-level, RNE)
__device__ __forceinline__ ushort f2bf(float v) {
    uint u = __float_as_uint(v);
    u += 0x7FFFu + ((u >> 16) & 1u);
    return (ushort)(u >> 16);
}
__device__ __forceinline__ float bf2f(ushort u) {
    return __uint_as_float(((uint)u) << 16);
}
__device__ __forceinline__ void fsplit(float v, ushort& h, ushort& l) {
    h = f2bf(v);
    l = f2bf(v - bf2f(h));
}

// ---------------------------------------------------------------- degree histogram
__global__ void k_deg(const int* __restrict__ tgt, int* __restrict__ deg) {
    int e = blockIdx.x * blockDim.x + threadIdx.x;
    if (e < N_EDGES) atomicAdd(&deg[tgt[e]], 1);
}

// ---------------------------------------------------------------- scan stage 1: block sums (+ dinv fused)
__global__ __launch_bounds__(256) void k_bsum(const int* __restrict__ deg,
                                              int* __restrict__ bsum,
                                              float* __restrict__ dinv) {
    __shared__ int ws[4];
    int idx = blockIdx.x * 256 + threadIdx.x;
    int v = (idx < N_NODES) ? deg[idx] : 0;
    if (idx < N_NODES) dinv[idx] = 1.0f / fmaxf((float)v, 1.0f);
    int s = v;
#pragma unroll
    for (int off = 1; off < 64; off <<= 1) s += __shfl_xor(s, off);
    if ((threadIdx.x & 63) == 0) ws[threadIdx.x >> 6] = s;
    __syncthreads();
    if (threadIdx.x == 0) bsum[blockIdx.x] = ws[0] + ws[1] + ws[2] + ws[3];
}

// ---------------------------------------------------------------- scan stage 2: scan the 196 block sums
__global__ __launch_bounds__(256) void k_bscan(const int* __restrict__ bsum,
                                               int* __restrict__ boff,
                                               int* __restrict__ rowptr) {
    __shared__ int ws[4];
    int t = threadIdx.x, lane = t & 63, w = t >> 6;
    int v = (t < NB) ? bsum[t] : 0;
    int incl = v;
#pragma unroll
    for (int off = 1; off < 64; off <<= 1) {
        int u = __shfl_up(incl, off);
        if (lane >= off) incl += u;
    }
    if (lane == 63) ws[w] = incl;
    __syncthreads();
    int wo = 0;
    if (w > 0) wo += ws[0];
    if (w > 1) wo += ws[1];
    if (w > 2) wo += ws[2];
    if (t < NB) boff[t] = wo + incl - v;
    if (t == 0) rowptr[N_NODES] = N_EDGES;   // total is known a priori
}

// ---------------------------------------------------------------- scan stage 3: block-local scan + offset
__global__ __launch_bounds__(256) void k_rowptr(const int* __restrict__ deg,
                                                const int* __restrict__ boff,
                                                int* __restrict__ rowptr) {
    __shared__ int ws[4];
    int b = blockIdx.x, t = threadIdx.x;
    int idx = b * 256 + t;
    int lane = t & 63, w = t >> 6;
    int v = (idx < N_NODES) ? deg[idx] : 0;
    int incl = v;
#pragma unroll
    for (int off = 1; off < 64; off <<= 1) {
        int u = __shfl_up(incl, off);
        if (lane >= off) incl += u;
    }
    if (lane == 63) ws[w] = incl;
    __syncthreads();
    int wo = 0;
    if (w > 0) wo += ws[0];
    if (w > 1) wo += ws[1];
    if (w > 2) wo += ws[2];
    if (idx < N_NODES) rowptr[idx] = boff[b] + wo + incl - v;
}

// ---------------------------------------------------------------- CSR fill
__global__ void k_fill(const int* __restrict__ src, const int* __restrict__ tgt,
                       const int* __restrict__ rowptr, int* __restrict__ fill,
                       int* __restrict__ csr_src) {
    int e = blockIdx.x * blockDim.x + threadIdx.x;
    if (e >= N_EDGES) return;
    int d = tgt[e];
    int pos = atomicAdd(&fill[d], 1);
    csr_src[rowptr[d] + pos] = src[e];
}

// ---------------------------------------------------------------- x -> hi/lo planes (cols 128..255 of 256-wide tables)
__global__ __launch_bounds__(256) void k_xsplit(const float* __restrict__ x,
                                                ushort* __restrict__ Ahi,
                                                ushort* __restrict__ Alo) {
    int gid = blockIdx.x * 256 + threadIdx.x;
    if (gid >= N_NODES * 32) return;
    int n = gid >> 5, c4 = (gid & 31) << 2;
    float4 v = *(const float4*)(x + (size_t)n * C + c4);
    ushort4 h, l;
    fsplit(v.x, h.x, l.x); fsplit(v.y, h.y, l.y);
    fsplit(v.z, h.z, l.z); fsplit(v.w, h.w, l.w);
    *(ushort4*)(Ahi + (size_t)n * 256 + 128 + c4) = h;
    *(ushort4*)(Alo + (size_t)n * 256 + 128 + c4) = l;
}

// ---------------------------------------------------------------- weights -> BT planes  BT[l][n][k] = k<128 ? wl[n][k] : wr[n][k-128]
struct WPtrs { const float* wl[4]; const float* wr[4]; };
__global__ __launch_bounds__(256) void k_wsplit(WPtrs wp, ushort* __restrict__ BTh,
                                                ushort* __restrict__ BTl) {
    int gid = blockIdx.x * 256 + threadIdx.x;   // 4*128*256 = 131072
    if (gid >= 4 * 128 * 256) return;
    int l = gid >> 15;
    int rem = gid & 32767;
    int n = rem >> 8, k = rem & 255;
    float v = (k < 128) ? wp.wl[l][n * 128 + k] : wp.wr[l][n * 128 + (k - 128)];
    ushort h, lo;
    fsplit(v, h, lo);
    BTh[gid] = h;
    BTl[gid] = lo;
}

// ---------------------------------------------------------------- gather-mean on planes (r5 version: best measured, MSHR-floor)
// 16 lanes per node, 16B (8-channel) loads per plane
// reads cols 128..255 (h of prev layer, hi+lo), writes cols 0..127 (agg split)
__global__ __launch_bounds__(256) void k_gather(const ushort* __restrict__ Ahi_r,
                                                const ushort* __restrict__ Alo_r,
                                                ushort* __restrict__ Ahi_w,
                                                ushort* __restrict__ Alo_w,
                                                const int* __restrict__ csr_src,
                                                const int* __restrict__ rowptr,
                                                const float* __restrict__ dinv) {
    int node = blockIdx.x * 16 + (threadIdx.x >> 4);
    if (node >= N_NODES) return;
    int c8 = (threadIdx.x & 15) << 3;   // 8-channel segment
    int s = rowptr[node], e = rowptr[node + 1];
    float a[8] = {0.f, 0.f, 0.f, 0.f, 0.f, 0.f, 0.f, 0.f};
    int j = s;
    for (; j + 3 < e; j += 4) {
        int s0 = csr_src[j], s1 = csr_src[j + 1];
        int s2 = csr_src[j + 2], s3 = csr_src[j + 3];
        bfrag8 h0 = *(const bfrag8*)(Ahi_r + (size_t)s0 * 256 + 128 + c8);
        bfrag8 l0 = *(const bfrag8*)(Alo_r + (size_t)s0 * 256 + 128 + c8);
        bfrag8 h1 = *(const bfrag8*)(Ahi_r + (size_t)s1 * 256 + 128 + c8);
        bfrag8 l1 = *(const bfrag8*)(Alo_r + (size_t)s1 * 256 + 128 + c8);
        bfrag8 h2 = *(const bfrag8*)(Ahi_r + (size_t)s2 * 256 + 128 + c8);
        bfrag8 l2 = *(const bfrag8*)(Alo_r + (size_t)s2 * 256 + 128 + c8);
        bfrag8 h3 = *(const bfrag8*)(Ahi_r + (size_t)s3 * 256 + 128 + c8);
        bfrag8 l3 = *(const bfrag8*)(Alo_r + (size_t)s3 * 256 + 128 + c8);
#pragma unroll
        for (int c = 0; c < 8; c++)
            a[c] += (bf2f((ushort)h0[c]) + bf2f((ushort)l0[c]))
                  + (bf2f((ushort)h1[c]) + bf2f((ushort)l1[c]))
                  + (bf2f((ushort)h2[c]) + bf2f((ushort)l2[c]))
                  + (bf2f((ushort)h3[c]) + bf2f((ushort)l3[c]));
    }
    for (; j < e; j++) {
        int s0 = csr_src[j];
        bfrag8 h0 = *(const bfrag8*)(Ahi_r + (size_t)s0 * 256 + 128 + c8);
        bfrag8 l0 = *(const bfrag8*)(Alo_r + (size_t)s0 * 256 + 128 + c8);
#pragma unroll
        for (int c = 0; c < 8; c++)
            a[c] += bf2f((ushort)h0[c]) + bf2f((ushort)l0[c]);
    }
    float sc = dinv[node];
    bfrag8 oh, ol;
#pragma unroll
    for (int c = 0; c < 8; c++) {
        float v = a[c] * sc;
        ushort hh, ll;
        fsplit(v, hh, ll);
        oh[c] = (short)hh;
        ol[c] = (short)ll;
    }
    *(bfrag8*)(Ahi_w + (size_t)node * 256 + c8) = oh;
    *(bfrag8*)(Alo_w + (size_t)node * 256 + c8) = ol;
}

// ---------------------------------------------------------------- split-bf16 MFMA GEMM (v4)
// D = Ahi·Bhi + Ahi·Blo + Alo·Bhi over K=256.
// BM=32, LDS=32KB -> 5 blocks/CU (20 waves) for latency hiding.
// A staged via ASYNC global_load_lds in fragment order: chunk id = wavebase+lane,
//   LDS dest = uniform base + lane*16 (exactly the HW constraint), global side
//   per-lane scattered. One barrier; barrier-free K-loop; LDS-staged epilogue.
// chunk id = p*1024 + mt*512 + s*64 + l ; l = ((k%32)/8)*16 + row%16
__global__ __launch_bounds__(256) void k_gemm(const ushort* __restrict__ Ahi,
                                              const ushort* __restrict__ Alo,
                                              const ushort* __restrict__ BTh,
                                              const ushort* __restrict__ BTl,
                                              const float* __restrict__ bl,
                                              ushort* __restrict__ Hhi,
                                              ushort* __restrict__ Hlo) {
    __shared__ __align__(16) short As[16384];   // 32KB
    const int tid = threadIdx.x;
    const int wave = tid >> 6, lane = tid & 63;
    const int m0 = blockIdx.x * 32;
    const int wn = wave * 32;
    const int l15 = lane & 15, lk = (lane >> 4) * 8;

    // ---- async stage A: 2048 chunks of 16B; wave w, iter i covers chunks (w*8+i)*64 .. +63
#pragma unroll
    for (int i = 0; i < 8; i++) {
        int cb = (wave * 8 + i) * 64;           // wave-uniform chunk base
        int id = cb + lane;
        int p = id >> 10, mt = (id >> 9) & 1, s = (id >> 6) & 7, l = id & 63;
        int row = m0 + mt * 16 + (l & 15);
        if (row >= N_NODES) row = N_NODES - 1;
        const ushort* gp = (p ? Alo : Ahi) + (size_t)row * 256 + s * 32 + (l >> 4) * 8;
        __builtin_amdgcn_global_load_lds(
            (const __attribute__((address_space(1))) uint*)gp,
            (__attribute__((address_space(3))) uint*)&As[cb * 8],
            16, 0, 0);
    }
    __syncthreads();

    // ---- B fragment pointers (per wave), L2-hot weight tile
    const ushort* pBh[2];
    const ushort* pBl[2];
#pragma unroll
    for (int t = 0; t < 2; t++) {
        int n = wn + t * 16 + l15;
        pBh[t] = BTh + n * 256 + lk;
        pBl[t] = BTl + n * 256 + lk;
    }

    // ---- barrier-free K-loop
    facc4 acc[2][2] = {};
#pragma unroll
    for (int s = 0; s < 8; s++) {
        bfrag8 bh[2], blv[2];
#pragma unroll
        for (int t = 0; t < 2; t++) {
            bh[t]  = *(const bfrag8*)(pBh[t] + s * 32);
            blv[t] = *(const bfrag8*)(pBl[t] + s * 32);
        }
        bfrag8 a0[2], a1[2];
#pragma unroll
        for (int mt = 0; mt < 2; mt++) {
            a0[mt] = *(const bfrag8*)&As[((mt * 8 + s) * 64 + lane) * 8];
            a1[mt] = *(const bfrag8*)&As[((16 + mt * 8 + s) * 64 + lane) * 8];
        }
#pragma unroll
        for (int mt = 0; mt < 2; mt++)
#pragma unroll
            for (int nt = 0; nt < 2; nt++) {
                acc[mt][nt] = __builtin_amdgcn_mfma_f32_16x16x32_bf16(a0[mt], bh[nt],  acc[mt][nt], 0, 0, 0);
                acc[mt][nt] = __builtin_amdgcn_mfma_f32_16x16x32_bf16(a0[mt], blv[nt], acc[mt][nt], 0, 0, 0);
                acc[mt][nt] = __builtin_amdgcn_mfma_f32_16x16x32_bf16(a1[mt], bh[nt],  acc[mt][nt], 0, 0, 0);
            }
    }
    __syncthreads();   // before LDS reuse

    // ---- epilogue: acc -> fp32 LDS (row stride 132 breaks pow2), coalesced 16B stores
    float* smf = (float*)As;            // 32 x 132 floats = 16.5KB
    const int r4 = (lane >> 4) * 4;
#pragma unroll
    for (int mt = 0; mt < 2; mt++)
#pragma unroll
        for (int nt = 0; nt < 2; nt++) {
            int cl = wn + nt * 16 + l15;
#pragma unroll
            for (int rr = 0; rr < 4; rr++) {
                int rl = mt * 16 + r4 + rr;
                smf[rl * 132 + cl] = acc[mt][nt][rr];
            }
        }
    __syncthreads();
    const int erow = tid >> 3;          // 0..31
    const int ecs = (tid & 7) * 16;     // col start
    int grow = m0 + erow;
    if (grow < N_NODES) {
        float vals[16];
#pragma unroll
        for (int q = 0; q < 4; q++) {
            float4 sv = *(const float4*)&smf[erow * 132 + ecs + q * 4];
            float4 bv = *(const float4*)(bl + ecs + q * 4);
            vals[q * 4 + 0] = fmaxf(sv.x + bv.x, 0.f);
            vals[q * 4 + 1] = fmaxf(sv.y + bv.y, 0.f);
            vals[q * 4 + 2] = fmaxf(sv.z + bv.z, 0.f);
            vals[q * 4 + 3] = fmaxf(sv.w + bv.w, 0.f);
        }
#pragma unroll
        for (int q = 0; q < 2; q++) {
            bfrag8 ho, lo;
#pragma unroll
            for (int c = 0; c < 8; c++) {
                ushort hh, ll;
                fsplit(vals[q * 8 + c], hh, ll);
                ho[c] = (short)hh;
                lo[c] = (short)ll;
            }
            *(bfrag8*)(Hhi + (size_t)grow * 256 + 128 + ecs + q * 8) = ho;
            *(bfrag8*)(Hlo + (size_t)grow * 256 + 128 + ecs + q * 8) = lo;
        }
    }
}

// ---------------------------------------------------------------- graph segment boundaries
__global__ void k_gstart(const int* __restrict__ batch, int* __restrict__ gstart) {
    int g = blockIdx.x * blockDim.x + threadIdx.x;
    if (g > N_GRAPHS) return;
    int lo = 0, hi = N_NODES;
    while (lo < hi) {
        int mid = (lo + hi) >> 1;
        if (batch[mid] < g) lo = mid + 1;
        else hi = mid;
    }
    gstart[g] = lo;
}

// ---------------------------------------------------------------- mean pool per graph (reads planes)
__global__ __launch_bounds__(512) void k_pool(const ushort* __restrict__ Ahi,
                                              const ushort* __restrict__ Alo,
                                              const int* __restrict__ gstart,
                                              float* __restrict__ gmean) {
    __shared__ float part[4][C];
    int g = blockIdx.x;
    int c = threadIdx.x & 127, p = threadIdx.x >> 7;
    int s = gstart[g], e = gstart[g + 1];
    float sum = 0.f;
    for (int n = s + p; n < e; n += 4) {
        size_t o = (size_t)n * 256 + 128 + c;
        sum += bf2f(Ahi[o]) + bf2f(Alo[o]);
    }
    part[p][c] = sum;
    __syncthreads();
    if (p == 0) {
        float tot = part[0][c] + part[1][c] + part[2][c] + part[3][c];
        float cnt = fmaxf((float)(e - s), 1.0f);
        gmean[g * C + c] = tot / cnt;
    }
}

// ---------------------------------------------------------------- classifier head
__global__ __launch_bounds__(256) void k_final(const ushort* __restrict__ Ahi,
                                               const ushort* __restrict__ Alo,
                                               const float* __restrict__ gmean,
                                               const int* __restrict__ root,
                                               const float* __restrict__ wcls,
                                               const float* __restrict__ bcls,
                                               float* __restrict__ out) {
    __shared__ float red[8];
    int g = blockIdx.x, t = threadIdx.x;
    float v;
    if (t < 128) {
        size_t o = (size_t)root[g] * 256 + 128 + t;
        v = bf2f(Ahi[o]) + bf2f(Alo[o]);
    } else {
        v = gmean[g * C + (t - 128)];
    }
    float p0 = v * wcls[t];
    float p1 = v * wcls[256 + t];
#pragma unroll
    for (int off = 32; off; off >>= 1) {
        p0 += __shfl_down(p0, off);
        p1 += __shfl_down(p1, off);
    }
    int wid = t >> 6;
    if ((t & 63) == 0) { red[wid] = p0; red[4 + wid] = p1; }
    __syncthreads();
    if (t == 0) {
        out[g * 2 + 0] = red[0] + red[1] + red[2] + red[3] + bcls[0];
        out[g * 2 + 1] = red[4] + red[5] + red[6] + red[7] + bcls[1];
    }
}

// ---------------------------------------------------------------- launch
extern "C" void kernel_launch(void* const* d_in, const int* in_sizes, int n_in,
                              void* d_out, int out_size, void* d_ws, size_t ws_size,
                              hipStream_t stream) {
    const float* x = (const float*)d_in[0];
    const int* ei = (const int*)d_in[1];
    const int* src = ei;
    const int* tgt = ei + N_EDGES;
    const int* root = (const int*)d_in[2];
    const int* batch = (const int*)d_in[3];
    WPtrs wp;
    wp.wl[0] = (const float*)d_in[4];  wp.wr[0] = (const float*)d_in[6];
    wp.wl[1] = (const float*)d_in[7];  wp.wr[1] = (const float*)d_in[9];
    wp.wl[2] = (const float*)d_in[10]; wp.wr[2] = (const float*)d_in[12];
    wp.wl[3] = (const float*)d_in[13]; wp.wr[3] = (const float*)d_in[15];
    const float* blv[4] = {(const float*)d_in[5], (const float*)d_in[8],
                           (const float*)d_in[11], (const float*)d_in[14]};
    const float* wcls = (const float*)d_in[16];
    const float* bcls = (const float*)d_in[17];
    float* out = (float*)d_out;

    // workspace carve-up (256-wide A tables: cols 0..127 agg, 128..255 h; in-place)
    ushort* Ahi = (ushort*)d_ws;                      // 50000*256 bf16
    ushort* Alo = Ahi + (size_t)N_NODES * 256;        // 50000*256
    ushort* BTh = Alo + (size_t)N_NODES * 256;        // 4*128*256
    ushort* BTl = BTh + 4 * 128 * 256;                // 4*128*256
    int* deg = (int*)(BTl + 4 * 128 * 256);           // 50000
    int* fill = deg + N_NODES;                        // 50000 (adjacent: one memset)
    float* dinv = (float*)(fill + N_NODES);           // 50000
    int* rowptr = (int*)(dinv + N_NODES);             // 50001
    int* csr_src = rowptr + N_NODES + 1;              // 600000
    int* bsum = csr_src + N_EDGES;                    // 196
    int* boff = bsum + 256;                           // 196
    int* gstart = boff + 256;                         // 257
    float* gmean = (float*)(gstart + 260);            // 256*128

    hipMemsetAsync(deg, 0, 2 * N_NODES * sizeof(int), stream);  // deg + fill
    k_deg<<<(N_EDGES + 255) / 256, 256, 0, stream>>>(tgt, deg);
    k_bsum<<<NB, 256, 0, stream>>>(deg, bsum, dinv);
    k_bscan<<<1, 256, 0, stream>>>(bsum, boff, rowptr);
    k_rowptr<<<NB, 256, 0, stream>>>(deg, boff, rowptr);
    k_fill<<<(N_EDGES + 255) / 256, 256, 0, stream>>>(src, tgt, rowptr, fill, csr_src);
    k_gstart<<<1, 512, 0, stream>>>(batch, gstart);
    k_xsplit<<<(N_NODES * 32 + 255) / 256, 256, 0, stream>>>(x, Ahi, Alo);
    k_wsplit<<<(4 * 128 * 256 + 255) / 256, 256, 0, stream>>>(wp, BTh, BTl);

    for (int l = 0; l < 4; l++) {
        k_gather<<<(N_NODES + 15) / 16, 256, 0, stream>>>(Ahi, Alo, Ahi, Alo,
                                                          csr_src, rowptr, dinv);
        k_gemm<<<(N_NODES + 31) / 32, 256, 0, stream>>>(
            Ahi, Alo, BTh + l * 32768, BTl + l * 32768, blv[l], Ahi, Alo);
    }
    k_pool<<<N_GRAPHS, 512, 0, stream>>>(Ahi, Alo, gstart, gmean);
    k_final<<<N_GRAPHS, 256, 0, stream>>>(Ahi, Alo, gmean, root, wcls, bcls, out);
}

// Round 10
// 483.941 us; speedup vs baseline: 1.1106x; 1.1106x over previous
//
#include <hip/hip_runtime.h>
#include <hip/hip_bf16.h>

#define N_NODES 50000
#define N_EDGES 600000
#define N_GRAPHS 256
#define C 128
#define NB 196            // ceil(N_NODES/256) scan blocks
// k_prep block ranges
#define PB_DEG 2344       // ceil(600000/256)
#define PB_XS  6250       // 50000*32/256
#define PB_WS  512        // 131072/256

typedef unsigned short ushort;
typedef unsigned int uint;
typedef __attribute__((ext_vector_type(8))) short bfrag8;
typedef __attribute__((ext_vector_type(4))) float facc4;

// bf16 helpers (bit-level, RNE)
__device__ __forceinline__ ushort f2bf(float v) {
    uint u = __float_as_uint(v);
    u += 0x7FFFu + ((u >> 16) & 1u);
    return (ushort)(u >> 16);
}
__device__ __forceinline__ float bf2f(ushort u) {
    return __uint_as_float(((uint)u) << 16);
}
__device__ __forceinline__ void fsplit(float v, ushort& h, ushort& l) {
    h = f2bf(v);
    l = f2bf(v - bf2f(h));
}

struct WPtrs { const float* wl[4]; const float* wr[4]; };

// ---------------------------------------------------------------- k_prep: deg atomics + xsplit + wsplit + gstart (range-partitioned)
__global__ __launch_bounds__(256) void k_prep(const int* __restrict__ tgt,
                                              int* __restrict__ deg,
                                              const float* __restrict__ x,
                                              ushort* __restrict__ Ahi,
                                              ushort* __restrict__ Alo,
                                              WPtrs wp,
                                              ushort* __restrict__ BTh,
                                              ushort* __restrict__ BTl,
                                              const int* __restrict__ batch,
                                              int* __restrict__ gstart) {
    const int b = blockIdx.x, t = threadIdx.x;
    if (b < PB_DEG) {
        int e = b * 256 + t;
        if (e < N_EDGES) atomicAdd(&deg[tgt[e]], 1);
    } else if (b < PB_DEG + PB_XS) {
        int gid = (b - PB_DEG) * 256 + t;      // < 1600000 exactly
        int n = gid >> 5, c4 = (gid & 31) << 2;
        float4 v = *(const float4*)(x + (size_t)n * C + c4);
        ushort4 h, l;
        fsplit(v.x, h.x, l.x); fsplit(v.y, h.y, l.y);
        fsplit(v.z, h.z, l.z); fsplit(v.w, h.w, l.w);
        *(ushort4*)(Ahi + (size_t)n * 256 + 128 + c4) = h;
        *(ushort4*)(Alo + (size_t)n * 256 + 128 + c4) = l;
    } else if (b < PB_DEG + PB_XS + PB_WS) {
        int gid = (b - PB_DEG - PB_XS) * 256 + t;   // < 131072 exactly
        int l = gid >> 15;
        int rem = gid & 32767;
        int n = rem >> 8, k = rem & 255;
        float v = (k < 128) ? wp.wl[l][n * 128 + k] : wp.wr[l][n * 128 + (k - 128)];
        ushort h, lo;
        fsplit(v, h, lo);
        BTh[gid] = h;
        BTl[gid] = lo;
    } else {
        // gstart: g = t (0..255) binary search on sorted batch; plus sentinel
        int g = t;
        int lo = 0, hi = N_NODES;
        while (lo < hi) {
            int mid = (lo + hi) >> 1;
            if (batch[mid] < g) lo = mid + 1;
            else hi = mid;
        }
        gstart[g] = lo;
        if (t == 0) gstart[N_GRAPHS] = N_NODES;
    }
}

// ---------------------------------------------------------------- scan stage 1: block sums (+ dinv fused)
__global__ __launch_bounds__(256) void k_scan1(const int* __restrict__ deg,
                                               int* __restrict__ bsum,
                                               float* __restrict__ dinv) {
    __shared__ int ws[4];
    int idx = blockIdx.x * 256 + threadIdx.x;
    int v = (idx < N_NODES) ? deg[idx] : 0;
    if (idx < N_NODES) dinv[idx] = 1.0f / fmaxf((float)v, 1.0f);
    int s = v;
#pragma unroll
    for (int off = 1; off < 64; off <<= 1) s += __shfl_xor(s, off);
    if ((threadIdx.x & 63) == 0) ws[threadIdx.x >> 6] = s;
    __syncthreads();
    if (threadIdx.x == 0) bsum[blockIdx.x] = ws[0] + ws[1] + ws[2] + ws[3];
}

// ---------------------------------------------------------------- scan stage 2: global offset (recomputed per block) + local scan -> rowptr
__global__ __launch_bounds__(256) void k_scan2(const int* __restrict__ deg,
                                               const int* __restrict__ bsum,
                                               int* __restrict__ rowptr) {
    __shared__ int red[4];
    __shared__ int ws[4];
    const int b = blockIdx.x, t = threadIdx.x;
    const int lane = t & 63, w = t >> 6;
    // block offset = sum of bsum[0..b)
    int bv = (t < NB && t < b) ? bsum[t] : 0;
#pragma unroll
    for (int off = 1; off < 64; off <<= 1) bv += __shfl_xor(bv, off);
    if (lane == 0) red[w] = bv;
    __syncthreads();
    const int boff = red[0] + red[1] + red[2] + red[3];
    // local exclusive scan
    int idx = b * 256 + t;
    int v = (idx < N_NODES) ? deg[idx] : 0;
    int incl = v;
#pragma unroll
    for (int off = 1; off < 64; off <<= 1) {
        int u = __shfl_up(incl, off);
        if (lane >= off) incl += u;
    }
    if (lane == 63) ws[w] = incl;
    __syncthreads();
    int wo = 0;
    if (w > 0) wo += ws[0];
    if (w > 1) wo += ws[1];
    if (w > 2) wo += ws[2];
    if (idx < N_NODES) rowptr[idx] = boff + wo + incl - v;
    if (b == 0 && t == 0) rowptr[N_NODES] = N_EDGES;
}

// ---------------------------------------------------------------- CSR fill
__global__ void k_fill(const int* __restrict__ src, const int* __restrict__ tgt,
                       const int* __restrict__ rowptr, int* __restrict__ fill,
                       int* __restrict__ csr_src) {
    int e = blockIdx.x * blockDim.x + threadIdx.x;
    if (e >= N_EDGES) return;
    int d = tgt[e];
    int pos = atomicAdd(&fill[d], 1);
    csr_src[rowptr[d] + pos] = src[e];
}

// ---------------------------------------------------------------- gather-mean on planes (r5 version: best measured, 45.0us)
// 32 lanes per node, ushort4 loads, 4-edge unroll
// reads cols 128..255 (h of prev layer, hi+lo), writes cols 0..127 (agg split)
__global__ __launch_bounds__(256) void k_gather(const ushort* __restrict__ Ahi_r,
                                                const ushort* __restrict__ Alo_r,
                                                ushort* __restrict__ Ahi_w,
                                                ushort* __restrict__ Alo_w,
                                                const int* __restrict__ csr_src,
                                                const int* __restrict__ rowptr,
                                                const float* __restrict__ dinv) {
    int node = blockIdx.x * 8 + (threadIdx.x >> 5);
    if (node >= N_NODES) return;
    int lane = threadIdx.x & 31;
    int c4 = lane << 2;
    int s = rowptr[node], e = rowptr[node + 1];
    float a0 = 0.f, a1 = 0.f, a2 = 0.f, a3 = 0.f;
    int j = s;
    for (; j + 3 < e; j += 4) {
        int s0 = csr_src[j], s1 = csr_src[j + 1];
        int s2 = csr_src[j + 2], s3 = csr_src[j + 3];
        ushort4 h0 = *(const ushort4*)(Ahi_r + (size_t)s0 * 256 + 128 + c4);
        ushort4 l0 = *(const ushort4*)(Alo_r + (size_t)s0 * 256 + 128 + c4);
        ushort4 h1 = *(const ushort4*)(Ahi_r + (size_t)s1 * 256 + 128 + c4);
        ushort4 l1 = *(const ushort4*)(Alo_r + (size_t)s1 * 256 + 128 + c4);
        ushort4 h2 = *(const ushort4*)(Ahi_r + (size_t)s2 * 256 + 128 + c4);
        ushort4 l2 = *(const ushort4*)(Alo_r + (size_t)s2 * 256 + 128 + c4);
        ushort4 h3 = *(const ushort4*)(Ahi_r + (size_t)s3 * 256 + 128 + c4);
        ushort4 l3 = *(const ushort4*)(Alo_r + (size_t)s3 * 256 + 128 + c4);
        a0 += (bf2f(h0.x) + bf2f(l0.x)) + (bf2f(h1.x) + bf2f(l1.x))
            + (bf2f(h2.x) + bf2f(l2.x)) + (bf2f(h3.x) + bf2f(l3.x));
        a1 += (bf2f(h0.y) + bf2f(l0.y)) + (bf2f(h1.y) + bf2f(l1.y))
            + (bf2f(h2.y) + bf2f(l2.y)) + (bf2f(h3.y) + bf2f(l3.y));
        a2 += (bf2f(h0.z) + bf2f(l0.z)) + (bf2f(h1.z) + bf2f(l1.z))
            + (bf2f(h2.z) + bf2f(l2.z)) + (bf2f(h3.z) + bf2f(l3.z));
        a3 += (bf2f(h0.w) + bf2f(l0.w)) + (bf2f(h1.w) + bf2f(l1.w))
            + (bf2f(h2.w) + bf2f(l2.w)) + (bf2f(h3.w) + bf2f(l3.w));
    }
    for (; j < e; j++) {
        int s0 = csr_src[j];
        ushort4 h0 = *(const ushort4*)(Ahi_r + (size_t)s0 * 256 + 128 + c4);
        ushort4 l0 = *(const ushort4*)(Alo_r + (size_t)s0 * 256 + 128 + c4);
        a0 += bf2f(h0.x) + bf2f(l0.x);
        a1 += bf2f(h0.y) + bf2f(l0.y);
        a2 += bf2f(h0.z) + bf2f(l0.z);
        a3 += bf2f(h0.w) + bf2f(l0.w);
    }
    float sc = dinv[node];
    a0 *= sc; a1 *= sc; a2 *= sc; a3 *= sc;
    ushort4 h, l;
    fsplit(a0, h.x, l.x); fsplit(a1, h.y, l.y);
    fsplit(a2, h.z, l.z); fsplit(a3, h.w, l.w);
    *(ushort4*)(Ahi_w + (size_t)node * 256 + c4) = h;
    *(ushort4*)(Alo_w + (size_t)node * 256 + c4) = l;
}

// ---------------------------------------------------------------- split-bf16 MFMA GEMM (r5 version: best measured)
// D = Ahi·Bhi + Ahi·Blo + Alo·Bhi over K=256; 128x128 block, 4 waves (2x2 of 64x64),
// register-prefetch pipelined staging.
__global__ __launch_bounds__(256) void k_gemm(const ushort* __restrict__ Ahi,
                                              const ushort* __restrict__ Alo,
                                              const ushort* __restrict__ BTh,
                                              const ushort* __restrict__ BTl,
                                              const float* __restrict__ bl,
                                              ushort* __restrict__ Hhi,
                                              ushort* __restrict__ Hlo) {
    __shared__ short As[2][128][40];
    __shared__ short Bs[2][128][40];
    const int tid = threadIdx.x;
    const int wave = tid >> 6, lane = tid & 63;
    const int m0 = blockIdx.x * 128;
    const int wm = (wave & 1) * 64;
    const int wn = (wave >> 1) * 64;
    const int l15 = lane & 15, lk = (lane >> 4) * 8;

    const int sr = tid >> 1;
    const int sc = (tid & 1) * 16;
    int garow = m0 + sr; if (garow >= N_NODES) garow = N_NODES - 1;
    const ushort* pAh = Ahi + (size_t)garow * 256 + sc;
    const ushort* pAl = Alo + (size_t)garow * 256 + sc;
    const ushort* pBh = BTh + sr * 256 + sc;
    const ushort* pBl = BTl + sr * 256 + sc;

    bfrag8 rAh0, rAh1, rAl0, rAl1, rBh0, rBh1, rBl0, rBl1;
#define LOADSTEP(K0) do { \
        rAh0 = *(const bfrag8*)(pAh + (K0));     rAh1 = *(const bfrag8*)(pAh + (K0) + 8); \
        rAl0 = *(const bfrag8*)(pAl + (K0));     rAl1 = *(const bfrag8*)(pAl + (K0) + 8); \
        rBh0 = *(const bfrag8*)(pBh + (K0));     rBh1 = *(const bfrag8*)(pBh + (K0) + 8); \
        rBl0 = *(const bfrag8*)(pBl + (K0));     rBl1 = *(const bfrag8*)(pBl + (K0) + 8); \
    } while (0)

    LOADSTEP(0);
    facc4 acc[4][4] = {};
#pragma unroll
    for (int s = 0; s < 8; s++) {
        *(bfrag8*)&As[0][sr][sc]     = rAh0;  *(bfrag8*)&As[0][sr][sc + 8] = rAh1;
        *(bfrag8*)&As[1][sr][sc]     = rAl0;  *(bfrag8*)&As[1][sr][sc + 8] = rAl1;
        *(bfrag8*)&Bs[0][sr][sc]     = rBh0;  *(bfrag8*)&Bs[0][sr][sc + 8] = rBh1;
        *(bfrag8*)&Bs[1][sr][sc]     = rBl0;  *(bfrag8*)&Bs[1][sr][sc + 8] = rBl1;
        __syncthreads();
        if (s < 7) LOADSTEP((s + 1) * 32);   // prefetch next K-step (overlaps MFMAs below)
        bfrag8 a[2][4], b[2][4];
#pragma unroll
        for (int t = 0; t < 4; t++) {
            a[0][t] = *(const bfrag8*)&As[0][wm + t * 16 + l15][lk];
            a[1][t] = *(const bfrag8*)&As[1][wm + t * 16 + l15][lk];
            b[0][t] = *(const bfrag8*)&Bs[0][wn + t * 16 + l15][lk];
            b[1][t] = *(const bfrag8*)&Bs[1][wn + t * 16 + l15][lk];
        }
#pragma unroll
        for (int mt = 0; mt < 4; mt++)
#pragma unroll
            for (int nt = 0; nt < 4; nt++) {
                acc[mt][nt] = __builtin_amdgcn_mfma_f32_16x16x32_bf16(a[0][mt], b[0][nt], acc[mt][nt], 0, 0, 0);
                acc[mt][nt] = __builtin_amdgcn_mfma_f32_16x16x32_bf16(a[0][mt], b[1][nt], acc[mt][nt], 0, 0, 0);
                acc[mt][nt] = __builtin_amdgcn_mfma_f32_16x16x32_bf16(a[1][mt], b[0][nt], acc[mt][nt], 0, 0, 0);
            }
        __syncthreads();
    }
#undef LOADSTEP

    // epilogue: bias + relu + split, write cols 128..255
    const int r4 = (lane >> 4) * 4;
#pragma unroll
    for (int mt = 0; mt < 4; mt++) {
#pragma unroll
        for (int nt = 0; nt < 4; nt++) {
            int col = wn + nt * 16 + l15;
            float bias = bl[col];
#pragma unroll
            for (int r = 0; r < 4; r++) {
                int grow = m0 + wm + mt * 16 + r4 + r;
                if (grow < N_NODES) {
                    float v = fmaxf(acc[mt][nt][r] + bias, 0.f);
                    ushort h, l;
                    fsplit(v, h, l);
                    Hhi[(size_t)grow * 256 + 128 + col] = h;
                    Hlo[(size_t)grow * 256 + 128 + col] = l;
                }
            }
        }
    }
}

// ---------------------------------------------------------------- k_head: mean-pool + classifier fused (one block per graph)
__global__ __launch_bounds__(256) void k_head(const ushort* __restrict__ Ahi,
                                              const ushort* __restrict__ Alo,
                                              const int* __restrict__ gstart,
                                              const int* __restrict__ root,
                                              const float* __restrict__ wcls,
                                              const float* __restrict__ bcls,
                                              float* __restrict__ out) {
    __shared__ float gm[128];
    __shared__ float part[128];
    __shared__ float red[8];
    const int g = blockIdx.x, t = threadIdx.x;
    const int c = t & 127, p = t >> 7;
    int s = gstart[g], e = gstart[g + 1];
    float sum = 0.f;
    for (int n = s + p; n < e; n += 2) {
        size_t o = (size_t)n * 256 + 128 + c;
        sum += bf2f(Ahi[o]) + bf2f(Alo[o]);
    }
    if (p) part[c] = sum;
    __syncthreads();
    if (!p) gm[c] = (sum + part[c]) / fmaxf((float)(e - s), 1.0f);
    __syncthreads();
    float v;
    if (t < 128) {
        size_t o = (size_t)root[g] * 256 + 128 + t;
        v = bf2f(Ahi[o]) + bf2f(Alo[o]);
    } else {
        v = gm[t - 128];
    }
    float p0 = v * wcls[t];
    float p1 = v * wcls[256 + t];
#pragma unroll
    for (int off = 32; off; off >>= 1) {
        p0 += __shfl_down(p0, off);
        p1 += __shfl_down(p1, off);
    }
    int wid = t >> 6;
    if ((t & 63) == 0) { red[wid] = p0; red[4 + wid] = p1; }
    __syncthreads();
    if (t == 0) {
        out[g * 2 + 0] = red[0] + red[1] + red[2] + red[3] + bcls[0];
        out[g * 2 + 1] = red[4] + red[5] + red[6] + red[7] + bcls[1];
    }
}

// ---------------------------------------------------------------- launch
extern "C" void kernel_launch(void* const* d_in, const int* in_sizes, int n_in,
                              void* d_out, int out_size, void* d_ws, size_t ws_size,
                              hipStream_t stream) {
    const float* x = (const float*)d_in[0];
    const int* ei = (const int*)d_in[1];
    const int* src = ei;
    const int* tgt = ei + N_EDGES;
    const int* root = (const int*)d_in[2];
    const int* batch = (const int*)d_in[3];
    WPtrs wp;
    wp.wl[0] = (const float*)d_in[4];  wp.wr[0] = (const float*)d_in[6];
    wp.wl[1] = (const float*)d_in[7];  wp.wr[1] = (const float*)d_in[9];
    wp.wl[2] = (const float*)d_in[10]; wp.wr[2] = (const float*)d_in[12];
    wp.wl[3] = (const float*)d_in[13]; wp.wr[3] = (const float*)d_in[15];
    const float* blv[4] = {(const float*)d_in[5], (const float*)d_in[8],
                           (const float*)d_in[11], (const float*)d_in[14]};
    const float* wcls = (const float*)d_in[16];
    const float* bcls = (const float*)d_in[17];
    float* out = (float*)d_out;

    // workspace carve-up (256-wide A tables: cols 0..127 agg, 128..255 h; in-place)
    ushort* Ahi = (ushort*)d_ws;                      // 50000*256 bf16
    ushort* Alo = Ahi + (size_t)N_NODES * 256;        // 50000*256
    ushort* BTh = Alo + (size_t)N_NODES * 256;        // 4*128*256
    ushort* BTl = BTh + 4 * 128 * 256;                // 4*128*256
    int* deg = (int*)(BTl + 4 * 128 * 256);           // 50000
    int* fill = deg + N_NODES;                        // 50000 (adjacent: one memset)
    float* dinv = (float*)(fill + N_NODES);           // 50000
    int* rowptr = (int*)(dinv + N_NODES);             // 50001
    int* csr_src = rowptr + N_NODES + 1;              // 600000
    int* bsum = csr_src + N_EDGES;                    // 196
    int* gstart = bsum + 256;                         // 257

    hipMemsetAsync(deg, 0, 2 * N_NODES * sizeof(int), stream);  // deg + fill
    k_prep<<<PB_DEG + PB_XS + PB_WS + 1, 256, 0, stream>>>(
        tgt, deg, x, Ahi, Alo, wp, BTh, BTl, batch, gstart);
    k_scan1<<<NB, 256, 0, stream>>>(deg, bsum, dinv);
    k_scan2<<<NB, 256, 0, stream>>>(deg, bsum, rowptr);
    k_fill<<<(N_EDGES + 255) / 256, 256, 0, stream>>>(src, tgt, rowptr, fill, csr_src);

    for (int l = 0; l < 4; l++) {
        k_gather<<<(N_NODES + 7) / 8, 256, 0, stream>>>(Ahi, Alo, Ahi, Alo,
                                                        csr_src, rowptr, dinv);
        k_gemm<<<(N_NODES + 127) / 128, 256, 0, stream>>>(
            Ahi, Alo, BTh + l * 32768, BTl + l * 32768, blv[l], Ahi, Alo);
    }
    k_head<<<N_GRAPHS, 256, 0, stream>>>(Ahi, Alo, gstart, root, wcls, bcls, out);
}